// Round 6
// baseline (94.811 us; speedup 1.0000x reference)
//
#include <hip/hip_runtime.h>
#include <hip/hip_bf16.h>

typedef __attribute__((ext_vector_type(8))) short bf16x8;   // 8 bf16 = 4 VGPRs
typedef __attribute__((ext_vector_type(4))) float f32x4;

#define BN 8192          // batch
#define DF 128           // feature dim
#define DG 64            // gathered dim
static constexpr float L2E = 1.44269504088896340736f;  // log2(e)
static constexpr float LN2 = 0.69314718055994530942f;

// Fragment-linear layout for the staged bf16 matrices:
// per 16-row tile (1024 shorts = 2KB): [half(2)][lane(64)][c(8)] where
// lane = q*16 + m encodes (row-in-tile m, k-group q), k = half*32 + q*8 + c.
// A wave's MFMA A/B fragment load is then base + lane*16B -> contiguous 1KB.
__device__ __forceinline__ size_t frag_off(int row, int d) {
  int tile = row >> 4, m = row & 15;
  int half = d >> 5, q = (d >> 3) & 3, c = d & 7;
  return (size_t)tile * 1024 + (size_t)half * 512 + (size_t)(q * 16 + m) * 8 + c;
}

// ---------------------------------------------------------------------------
// Kernel 1: gather columns, convert to bf16 (X-side pre-scaled by log2 e),
// write fragment-linear layout, exact fp32 diagonals, zero rowsum + d_out.
// One wave per row. Rows are loaded COALESCED (float2/lane) and the random
// column gather is done in-register via __shfl (8 bpermutes + 4 selects)
// instead of 4 scattered per-lane loads (~32 L1 txns each) -- Round-6 change.
// ---------------------------------------------------------------------------
__global__ __launch_bounds__(256) void gather_k(
    const float* __restrict__ a, const float* __restrict__ v,
    const int* __restrict__ aidx, const int* __restrict__ iidx,
    __hip_bfloat16* __restrict__ Xv, __hip_bfloat16* __restrict__ Ya,
    __hip_bfloat16* __restrict__ Xa, __hip_bfloat16* __restrict__ Yv,
    float* __restrict__ diag, float* __restrict__ rowsum,
    float* __restrict__ out) {
  int tid = threadIdx.x;
  int gid = blockIdx.x * 256 + tid;
  if (gid < 2 * BN) rowsum[gid] = 0.f;    // zero accumulators (ws is poisoned)
  if (gid == 0) out[0] = 0.f;             // d_out is poisoned too

  int lane = tid & 63;
  int row  = blockIdx.x * 4 + (tid >> 6); // 2048 blocks x 4 waves = 8192 rows
  int ka = aidx[lane];
  int ki = iidx[lane];

  // coalesced: lane l holds elements (2l, 2l+1) of this row of a and v
  float2 a2 = ((const float2*)(a + (size_t)row * DF))[lane];
  float2 v2 = ((const float2*)(v + (size_t)row * DF))[lane];

  // in-register gather: element k lives in lane k>>1, component k&1
  float axa = __shfl(a2.x, ka >> 1), aya = __shfl(a2.y, ka >> 1);
  float vxa = __shfl(v2.x, ka >> 1), vya = __shfl(v2.y, ka >> 1);
  float axi = __shfl(a2.x, ki >> 1), ayi = __shfl(a2.y, ki >> 1);
  float vxi = __shfl(v2.x, ki >> 1), vyi = __shfl(v2.y, ki >> 1);
  float aa = (ka & 1) ? aya : axa;   // audio_only        (S_v cols)
  float va = (ka & 1) ? vya : vxa;   // image_audio_only  (S_v rows)
  float ai = (ki & 1) ? ayi : axi;   // audio_image_only  (S_a rows)
  float vi = (ki & 1) ? vyi : vxi;   // image_only        (S_a cols)

  size_t fo = frag_off(row, lane);
  Xv[fo] = __float2bfloat16(va * L2E);
  Ya[fo] = __float2bfloat16(aa);
  Xa[fo] = __float2bfloat16(ai * L2E);
  Yv[fo] = __float2bfloat16(vi);

  // exact fp32 diagonals: diag_v[i] = dot(v_gath_a[i], a_gath_a[i]), etc.
  float dv = va * aa;
  float da = ai * vi;
#pragma unroll
  for (int off = 32; off >= 1; off >>= 1) {
    dv += __shfl_xor(dv, off);
    da += __shfl_xor(da, off);
  }
  if (lane == 0) {
    diag[row]      = dv;
    diag[BN + row] = da;
  }
}

// ---------------------------------------------------------------------------
// Kernel 2: for each row i compute partial sum_j 2^(S_ij) with S in log2
// domain via mfma_f32_16x16x32_bf16. Grid: (rows/256, 16 col-slices, 2 loss).
// Each wave owns 64 rows (4 MFMA row-tiles), loops over 32 j-tiles (512 cols).
// No waves/EU cap this round: grid (1024 blocks = 4/CU) already bounds
// occupancy, and the cap risked forced spills in the hot loop.
// C layout: col = lane&15, row = quad*4 + reg.
// ---------------------------------------------------------------------------
__global__ __launch_bounds__(256) void lse_main(
    const unsigned short* __restrict__ Xv, const unsigned short* __restrict__ Ya,
    const unsigned short* __restrict__ Xa, const unsigned short* __restrict__ Yv,
    float* __restrict__ rowsum) {
  const unsigned short* X;
  const unsigned short* Y;
  float* rs;
  if (blockIdx.z == 0) { X = Xv; Y = Ya; rs = rowsum; }
  else                 { X = Xa; Y = Yv; rs = rowsum + BN; }

  int tid  = threadIdx.x;
  int lane = tid & 63;
  int m = lane & 15;        // C: col within j-tile
  int q = lane >> 4;        // C: row group
  int row0 = blockIdx.x * 256 + (tid >> 6) * 64;   // 4 row-tiles per wave

  // A fragments for this wave's 4 row-tiles (K=64 -> 2 halves per tile)
  bf16x8 af[4][2];
#pragma unroll
  for (int t = 0; t < 4; ++t) {
    const unsigned short* p =
        X + (size_t)(row0 / 16 + t) * 1024 + (size_t)lane * 8;
    af[t][0] = *(const bf16x8*)p;
    af[t][1] = *(const bf16x8*)(p + 512);
  }

  f32x4 part[4] = {};
  const f32x4 zero = {0.f, 0.f, 0.f, 0.f};

  // this block's B base: 512 cols = 32 j-tiles; tile stride = 1024 shorts
  const unsigned short* bbase =
      Y + (size_t)(blockIdx.y * 32) * 1024 + (size_t)lane * 8;
  bf16x8 b0 = *(const bf16x8*)bbase;
  bf16x8 b1 = *(const bf16x8*)(bbase + 512);

  for (int jt = 0; jt < 32; ++jt) {
    // prefetch next B fragment (clamped; redundant reload on last iter)
    int jn = (jt < 31) ? jt + 1 : 31;
    const unsigned short* np = bbase + (size_t)jn * 1024;
    bf16x8 n0 = *(const bf16x8*)np;
    bf16x8 n1 = *(const bf16x8*)(np + 512);
#pragma unroll
    for (int t = 0; t < 4; ++t) {
      f32x4 c = __builtin_amdgcn_mfma_f32_16x16x32_bf16(af[t][0], b0, zero, 0, 0, 0);
      c = __builtin_amdgcn_mfma_f32_16x16x32_bf16(af[t][1], b1, c, 0, 0, 0);
      f32x4 e;
      e[0] = __builtin_amdgcn_exp2f(c[0]);
      e[1] = __builtin_amdgcn_exp2f(c[1]);
      e[2] = __builtin_amdgcn_exp2f(c[2]);
      e[3] = __builtin_amdgcn_exp2f(c[3]);
      part[t] += e;
    }
    b0 = n0;
    b1 = n1;
  }

  // row sums are spread across the 16 lanes of each quad -> xor-shuffle reduce
#pragma unroll
  for (int off = 1; off < 16; off <<= 1) {
#pragma unroll
    for (int t = 0; t < 4; ++t) {
#pragma unroll
      for (int r = 0; r < 4; ++r)
        part[t][r] += __shfl_xor(part[t][r], off);
    }
  }
  if (m == 0) {
#pragma unroll
    for (int t = 0; t < 4; ++t)
#pragma unroll
      for (int r = 0; r < 4; ++r)
        atomicAdd(&rs[row0 + t * 16 + q * 4 + r], part[t][r]);
  }
}

// ---------------------------------------------------------------------------
// Kernel 3: 64-block finalize: out += sum(ln2*log2(rowsum) - diag) / BN
// (d_out zeroed by gather_k). __builtin_amdgcn_logf IS v_log_f32 = log2.
// ---------------------------------------------------------------------------
__global__ __launch_bounds__(256) void finalize_k(
    const float* __restrict__ rowsum, const float* __restrict__ diag,
    float* __restrict__ out) {
  int i = blockIdx.x * 256 + threadIdx.x;          // 64*256 = 16384 = 2*BN
  float local = LN2 * __builtin_amdgcn_logf(rowsum[i]) - diag[i];
#pragma unroll
  for (int off = 32; off >= 1; off >>= 1) local += __shfl_xor(local, off);
  __shared__ float red[4];
  int wave = threadIdx.x >> 6;
  if ((threadIdx.x & 63) == 0) red[wave] = local;
  __syncthreads();
  if (threadIdx.x == 0) {
    float bs = red[0] + red[1] + red[2] + red[3];
    atomicAdd(out, bs * (1.f / (float)BN));
  }
}

// ---------------------------------------------------------------------------
extern "C" void kernel_launch(void* const* d_in, const int* in_sizes, int n_in,
                              void* d_out, int out_size, void* d_ws, size_t ws_size,
                              hipStream_t stream) {
  const float* a   = (const float*)d_in[0];
  const float* v   = (const float*)d_in[1];
  const int* aidx  = (const int*)d_in[2];
  const int* iidx  = (const int*)d_in[3];
  // d_in[4] = labels (unused by the loss)

  char* ws = (char*)d_ws;
  const size_t MB = 1024 * 1024;
  __hip_bfloat16* Xv = (__hip_bfloat16*)(ws + 0 * MB);
  __hip_bfloat16* Ya = (__hip_bfloat16*)(ws + 1 * MB);
  __hip_bfloat16* Xa = (__hip_bfloat16*)(ws + 2 * MB);
  __hip_bfloat16* Yv = (__hip_bfloat16*)(ws + 3 * MB);
  float* diag   = (float*)(ws + 4 * MB);             // [2][8192]
  float* rowsum = (float*)(ws + 4 * MB + 64 * 1024); // [2][8192]

  gather_k<<<BN / 4, 256, 0, stream>>>(a, v, aidx, iidx, Xv, Ya, Xa, Yv,
                                       diag, rowsum, (float*)d_out);
  lse_main<<<dim3(BN / 256, 16, 2), 256, 0, stream>>>(
      (const unsigned short*)Xv, (const unsigned short*)Ya,
      (const unsigned short*)Xa, (const unsigned short*)Yv, rowsum);
  finalize_k<<<64, 256, 0, stream>>>(rowsum, diag, (float*)d_out);
}

// Round 7
// 92.390 us; speedup vs baseline: 1.0262x; 1.0262x over previous
//
#include <hip/hip_runtime.h>
#include <hip/hip_bf16.h>

typedef __attribute__((ext_vector_type(8))) short bf16x8;   // 8 bf16 = 4 VGPRs
typedef __attribute__((ext_vector_type(4))) float f32x4;

#define BN 8192          // batch
#define DF 128           // feature dim
#define DG 64            // gathered dim
static constexpr float L2E = 1.44269504088896340736f;  // log2(e)
static constexpr float LN2 = 0.69314718055994530942f;

// Fragment-linear layout for the staged bf16 matrices:
// per 16-row tile (1024 shorts = 2KB): [half(2)][lane(64)][c(8)] where
// lane = q*16 + m encodes (row-in-tile m, k-group q), k = half*32 + q*8 + c.
// A wave's MFMA A/B fragment load is then base + lane*16B -> contiguous 1KB.
__device__ __forceinline__ size_t frag_off(int row, int d) {
  int tile = row >> 4, m = row & 15;
  int half = d >> 5, q = (d >> 3) & 3, c = d & 7;
  return (size_t)tile * 1024 + (size_t)half * 512 + (size_t)(q * 16 + m) * 8 + c;
}

// ---------------------------------------------------------------------------
// Kernel 1: gather columns, convert to bf16 (X-side pre-scaled by log2 e),
// write fragment-linear layout, exact fp32 diagonals, zero rowsum + d_out.
// One wave per row; coalesced float2 row loads + in-register __shfl gather.
// ---------------------------------------------------------------------------
__global__ __launch_bounds__(256) void gather_k(
    const float* __restrict__ a, const float* __restrict__ v,
    const int* __restrict__ aidx, const int* __restrict__ iidx,
    __hip_bfloat16* __restrict__ Xv, __hip_bfloat16* __restrict__ Ya,
    __hip_bfloat16* __restrict__ Xa, __hip_bfloat16* __restrict__ Yv,
    float* __restrict__ diag, float* __restrict__ rowsum,
    float* __restrict__ out) {
  int tid = threadIdx.x;
  int gid = blockIdx.x * 256 + tid;
  if (gid < 2 * BN) rowsum[gid] = 0.f;    // zero accumulators (ws is poisoned)
  if (gid == 0) out[0] = 0.f;             // d_out is poisoned too

  int lane = tid & 63;
  int row  = blockIdx.x * 4 + (tid >> 6); // 2048 blocks x 4 waves = 8192 rows
  int ka = aidx[lane];
  int ki = iidx[lane];

  // coalesced: lane l holds elements (2l, 2l+1) of this row of a and v
  float2 a2 = ((const float2*)(a + (size_t)row * DF))[lane];
  float2 v2 = ((const float2*)(v + (size_t)row * DF))[lane];

  // in-register gather: element k lives in lane k>>1, component k&1
  float axa = __shfl(a2.x, ka >> 1), aya = __shfl(a2.y, ka >> 1);
  float vxa = __shfl(v2.x, ka >> 1), vya = __shfl(v2.y, ka >> 1);
  float axi = __shfl(a2.x, ki >> 1), ayi = __shfl(a2.y, ki >> 1);
  float vxi = __shfl(v2.x, ki >> 1), vyi = __shfl(v2.y, ki >> 1);
  float aa = (ka & 1) ? aya : axa;   // audio_only        (S_v cols)
  float va = (ka & 1) ? vya : vxa;   // image_audio_only  (S_v rows)
  float ai = (ki & 1) ? ayi : axi;   // audio_image_only  (S_a rows)
  float vi = (ki & 1) ? vyi : vxi;   // image_only        (S_a cols)

  size_t fo = frag_off(row, lane);
  Xv[fo] = __float2bfloat16(va * L2E);
  Ya[fo] = __float2bfloat16(aa);
  Xa[fo] = __float2bfloat16(ai * L2E);
  Yv[fo] = __float2bfloat16(vi);

  // exact fp32 diagonals: diag_v[i] = dot(v_gath_a[i], a_gath_a[i]), etc.
  float dv = va * aa;
  float da = ai * vi;
#pragma unroll
  for (int off = 32; off >= 1; off >>= 1) {
    dv += __shfl_xor(dv, off);
    da += __shfl_xor(da, off);
  }
  if (lane == 0) {
    diag[row]      = dv;
    diag[BN + row] = da;
  }
}

// ---------------------------------------------------------------------------
// Kernel 2: partial sum_j 2^(S_ij) via mfma_f32_16x16x32_bf16.
// Round-7 change: occupancy 4 -> 8 waves/SIMD. Grid (rows/128, 16, 2) = 2048
// blocks = 8 blocks/CU; each wave owns 32 rows (t=2). Same total instruction
// count as Round 6 but 2x the waves to hide the load->MFMA->exp dependency
// chain (R5 proved we're not BW-bound; R6 showed 4 waves/SIMD leaves ~65%
// issue idle). __launch_bounds__(256,8) caps VGPR at 64 (est. usage ~55).
// C layout: col = lane&15, row = quad*4 + reg.
// ---------------------------------------------------------------------------
__global__ __launch_bounds__(256, 8) void lse_main(
    const unsigned short* __restrict__ Xv, const unsigned short* __restrict__ Ya,
    const unsigned short* __restrict__ Xa, const unsigned short* __restrict__ Yv,
    float* __restrict__ rowsum) {
  const unsigned short* X;
  const unsigned short* Y;
  float* rs;
  if (blockIdx.z == 0) { X = Xv; Y = Ya; rs = rowsum; }
  else                 { X = Xa; Y = Yv; rs = rowsum + BN; }

  int tid  = threadIdx.x;
  int lane = tid & 63;
  int m = lane & 15;        // C: col within j-tile
  int q = lane >> 4;        // C: row group
  int row0 = blockIdx.x * 128 + (tid >> 6) * 32;   // 2 row-tiles per wave

  // A fragments for this wave's 2 row-tiles (K=64 -> 2 halves per tile)
  bf16x8 af[2][2];
#pragma unroll
  for (int t = 0; t < 2; ++t) {
    const unsigned short* p =
        X + (size_t)(row0 / 16 + t) * 1024 + (size_t)lane * 8;
    af[t][0] = *(const bf16x8*)p;
    af[t][1] = *(const bf16x8*)(p + 512);
  }

  f32x4 part[2] = {};
  const f32x4 zero = {0.f, 0.f, 0.f, 0.f};

  // this block's B base: 512 cols = 32 j-tiles; tile stride = 1024 shorts
  const unsigned short* bbase =
      Y + (size_t)(blockIdx.y * 32) * 1024 + (size_t)lane * 8;
  bf16x8 b0 = *(const bf16x8*)bbase;
  bf16x8 b1 = *(const bf16x8*)(bbase + 512);

#define LSE_BODY(B0, B1)                                                      \
  {                                                                           \
    _Pragma("unroll") for (int t = 0; t < 2; ++t) {                           \
      f32x4 c =                                                               \
          __builtin_amdgcn_mfma_f32_16x16x32_bf16(af[t][0], B0, zero, 0, 0, 0); \
      c = __builtin_amdgcn_mfma_f32_16x16x32_bf16(af[t][1], B1, c, 0, 0, 0);  \
      f32x4 e;                                                                \
      e[0] = __builtin_amdgcn_exp2f(c[0]);                                    \
      e[1] = __builtin_amdgcn_exp2f(c[1]);                                    \
      e[2] = __builtin_amdgcn_exp2f(c[2]);                                    \
      e[3] = __builtin_amdgcn_exp2f(c[3]);                                    \
      part[t] += e;                                                           \
    }                                                                         \
  }

  // 31 pipelined iterations + peeled epilogue (no per-iter clamp math)
  for (int jt = 0; jt < 31; ++jt) {
    const unsigned short* np = bbase + (size_t)(jt + 1) * 1024;
    bf16x8 n0 = *(const bf16x8*)np;
    bf16x8 n1 = *(const bf16x8*)(np + 512);
    LSE_BODY(b0, b1)
    b0 = n0;
    b1 = n1;
  }
  LSE_BODY(b0, b1)
#undef LSE_BODY

  // row sums are spread across the 16 lanes of each quad -> xor-shuffle reduce
#pragma unroll
  for (int off = 1; off < 16; off <<= 1) {
#pragma unroll
    for (int t = 0; t < 2; ++t) {
#pragma unroll
      for (int r = 0; r < 4; ++r)
        part[t][r] += __shfl_xor(part[t][r], off);
    }
  }
  if (m == 0) {
#pragma unroll
    for (int t = 0; t < 2; ++t)
#pragma unroll
      for (int r = 0; r < 4; ++r)
        atomicAdd(&rs[row0 + t * 16 + q * 4 + r], part[t][r]);
  }
}

// ---------------------------------------------------------------------------
// Kernel 3: 64-block finalize: out += sum(ln2*log2(rowsum) - diag) / BN
// (d_out zeroed by gather_k). __builtin_amdgcn_logf IS v_log_f32 = log2.
// ---------------------------------------------------------------------------
__global__ __launch_bounds__(256) void finalize_k(
    const float* __restrict__ rowsum, const float* __restrict__ diag,
    float* __restrict__ out) {
  int i = blockIdx.x * 256 + threadIdx.x;          // 64*256 = 16384 = 2*BN
  float local = LN2 * __builtin_amdgcn_logf(rowsum[i]) - diag[i];
#pragma unroll
  for (int off = 32; off >= 1; off >>= 1) local += __shfl_xor(local, off);
  __shared__ float red[4];
  int wave = threadIdx.x >> 6;
  if ((threadIdx.x & 63) == 0) red[wave] = local;
  __syncthreads();
  if (threadIdx.x == 0) {
    float bs = red[0] + red[1] + red[2] + red[3];
    atomicAdd(out, bs * (1.f / (float)BN));
  }
}

// ---------------------------------------------------------------------------
extern "C" void kernel_launch(void* const* d_in, const int* in_sizes, int n_in,
                              void* d_out, int out_size, void* d_ws, size_t ws_size,
                              hipStream_t stream) {
  const float* a   = (const float*)d_in[0];
  const float* v   = (const float*)d_in[1];
  const int* aidx  = (const int*)d_in[2];
  const int* iidx  = (const int*)d_in[3];
  // d_in[4] = labels (unused by the loss)

  char* ws = (char*)d_ws;
  const size_t MB = 1024 * 1024;
  __hip_bfloat16* Xv = (__hip_bfloat16*)(ws + 0 * MB);
  __hip_bfloat16* Ya = (__hip_bfloat16*)(ws + 1 * MB);
  __hip_bfloat16* Xa = (__hip_bfloat16*)(ws + 2 * MB);
  __hip_bfloat16* Yv = (__hip_bfloat16*)(ws + 3 * MB);
  float* diag   = (float*)(ws + 4 * MB);             // [2][8192]
  float* rowsum = (float*)(ws + 4 * MB + 64 * 1024); // [2][8192]

  gather_k<<<BN / 4, 256, 0, stream>>>(a, v, aidx, iidx, Xv, Ya, Xa, Yv,
                                       diag, rowsum, (float*)d_out);
  lse_main<<<dim3(BN / 128, 16, 2), 256, 0, stream>>>(
      (const unsigned short*)Xv, (const unsigned short*)Ya,
      (const unsigned short*)Xa, (const unsigned short*)Yv, rowsum);
  finalize_k<<<64, 256, 0, stream>>>(rowsum, diag, (float*)d_out);
}